// Round 12
// baseline (154.710 us; speedup 1.0000x reference)
//
#include <hip/hip_runtime.h>

#define IN_DIM 128
#define OUT_DIM 128

typedef __attribute__((ext_vector_type(8))) short short8v;   // 8 bf16 = 4 VGPRs
typedef __attribute__((ext_vector_type(4))) float float4v;
typedef __attribute__((ext_vector_type(4))) unsigned int uint4v;

__device__ __forceinline__ ushort f2bf(float f) {
    unsigned int u = __builtin_bit_cast(unsigned int, f);
    unsigned int r = (u + 0x7fffu + ((u >> 16) & 1u)) >> 16;   // RNE
    return (ushort)r;
}

__device__ __forceinline__ unsigned int pk2bf(float x, float y) {
#if __has_builtin(__builtin_amdgcn_cvt_pk_bf16_f32)
    typedef __attribute__((ext_vector_type(2))) __bf16 bf2;
    bf2 r = __builtin_amdgcn_cvt_pk_bf16_f32(x, y);
    return __builtin_bit_cast(unsigned int, r);
#else
    return (unsigned int)f2bf(x) | ((unsigned int)f2bf(y) << 16);
#endif
}

// ---------------- Kernel 0: prep (Wt only, 16 blocks) ----------------
// Wt[n][k] = bf16(W[k][n]), row stride 136. Coalesced fp32 reads, b32 stores.
__global__ __launch_bounds__(256) void prep_kernel(const float* __restrict__ W,
                                                   ushort* __restrict__ Wt) {
    int k0 = blockIdx.x * 8;
    int n = threadIdx.x & 127;
    int half = threadIdx.x >> 7;
#pragma unroll
    for (int kp = 0; kp < 2; ++kp) {
        int k = k0 + (half * 2 + kp) * 2;
        float v0 = W[k * 128 + n];          // coalesced across lanes
        float v1 = W[(k + 1) * 128 + n];
        *(unsigned int*)&Wt[n * 136 + k] = pk2bf(v0, v1);
    }
}

// ---------------- Kernel 1: T(biased-uint8, per-row scale) = H @ W, + rp tail ----------------
// Blocks [0, nb_gemm): 64-row x 128-col tile, K=128 unrolled (proven core).
// Epilogue: per-row absmax (shfl_xor 16/32 over quarter-lanes), quantize row
// to BIASED uint8 (q+128), scale S[row] = rowmax/127. Output is SPLIT into
// two arrays (cols 0-63 -> Tlo, 64-127 -> Thi), each row 64 B, so each
// half is a physically separate 3.2 MB region that fits a 4-MiB XCD L2
// (R8's in-place column split failed: 64-B halves shared 128-B lines).
// Blocks [nb_gemm, ...): row_ptr[n] = lower_bound(edst, n) (overlaps gemm).
__global__ __launch_bounds__(256) void gemm_kernel(const float* __restrict__ H,
                                                   const ushort* __restrict__ Wt_g,
                                                   unsigned char* __restrict__ Tlo,
                                                   unsigned char* __restrict__ Thi,
                                                   float* __restrict__ S, int M,
                                                   const int* __restrict__ edst,
                                                   int* __restrict__ rp,
                                                   int E, int nb_gemm) {
    __shared__ ushort Ws[128 * 136];   // 34816 B

    const int t = threadIdx.x;

    if (blockIdx.x >= nb_gemm) {       // rp tail blocks (block-uniform branch)
        int n = (blockIdx.x - nb_gemm) * 256 + t;
        if (n <= M) {
            int lo = 0, hi = E;
            while (lo < hi) {
                int mid = (lo + hi) >> 1;
                if (edst[mid] < n) lo = mid + 1; else hi = mid;
            }
            rp[n] = lo;
        }
        return;
    }

    const int row0 = blockIdx.x * 64;

#pragma unroll
    for (int f = t; f < 2176; f += 256)
        ((short8v*)Ws)[f] = ((const short8v*)Wt_g)[f];

    const int w = t >> 6;
    const int l = t & 63;
    const int m16 = l & 15;
    const int kq = (l >> 4) * 8;
    const int gr = row0 + w * 16 + m16;

    float4 h[8];
    if (gr < M) {
#pragma unroll
        for (int ks = 0; ks < 4; ++ks) {
            h[ks * 2]     = *(const float4*)&H[gr * 128 + ks * 32 + kq];
            h[ks * 2 + 1] = *(const float4*)&H[gr * 128 + ks * 32 + kq + 4];
        }
    } else {
#pragma unroll
        for (int i = 0; i < 8; ++i) h[i] = make_float4(0.f, 0.f, 0.f, 0.f);
    }

    short8v bfrag[4];
#pragma unroll
    for (int ks = 0; ks < 4; ++ks) {
        uint4v u;
        u[0] = pk2bf(h[ks * 2].x, h[ks * 2].y);
        u[1] = pk2bf(h[ks * 2].z, h[ks * 2].w);
        u[2] = pk2bf(h[ks * 2 + 1].x, h[ks * 2 + 1].y);
        u[3] = pk2bf(h[ks * 2 + 1].z, h[ks * 2 + 1].w);
        bfrag[ks] = __builtin_bit_cast(short8v, u);
    }

    __syncthreads();   // Ws ready

    float4v acc[8];
#pragma unroll
    for (int nt = 0; nt < 8; ++nt) acc[nt] = (float4v){0.f, 0.f, 0.f, 0.f};

#pragma unroll
    for (int ks = 0; ks < 4; ++ks) {
#pragma unroll
        for (int nt = 0; nt < 8; ++nt) {
            short8v afrag = *(const short8v*)&Ws[(nt * 16 + m16) * 136 + ks * 32 + kq];
            acc[nt] = __builtin_amdgcn_mfma_f32_16x16x32_bf16(afrag, bfrag[ks], acc[nt], 0, 0, 0);
        }
    }

    // Per-row absmax across this lane's 32 cols, then across the 4 quarter-
    // lanes sharing row gr (l, l^16, l^32, l^48).
    float mx = 0.f;
#pragma unroll
    for (int nt = 0; nt < 8; ++nt) {
#pragma unroll
        for (int k = 0; k < 4; ++k) mx = fmaxf(mx, fabsf(acc[nt][k]));
    }
    mx = fmaxf(mx, __shfl_xor(mx, 16));
    mx = fmaxf(mx, __shfl_xor(mx, 32));

    const float inv = 127.0f / fmaxf(mx, 1e-20f);

    if (gr < M) {
        const int qd = l >> 4;
        if (qd == 0) S[gr] = mx * (1.0f / 127.0f);
#pragma unroll
        for (int nt = 0; nt < 8; ++nt) {
            unsigned int p = 0;
#pragma unroll
            for (int k = 0; k < 4; ++k) {
                int qi = (int)__builtin_rintf(acc[nt][k] * inv);
                qi = qi > 127 ? 127 : (qi < -127 ? -127 : qi);
                p |= ((unsigned int)(qi + 128) & 0xffu) << (k * 8);   // biased
            }
            const int col = nt * 16 + qd * 4;
            if (nt < 4)
                *(unsigned int*)&Tlo[gr * 64 + col] = p;
            else
                *(unsigned int*)&Thi[gr * 64 + (col - 64)] = p;
        }
    }
}

// ---------------- Kernel 2: out[n][:] = b + sum_{e} w_e*S[src]*(T[src][:]-128) ----------------
// SPLIT-T + XCD AFFINITY: each block handles one 64-col half of 4 nodes,
// gathering from its half's PHYSICALLY SEPARATE 3.2 MB array (64-B rows).
// blockIdx&7 round-robins over XCDs -> XCDs 0-3 touch only Tlo, 4-7 only
// Thi; each slice is L2-RESIDENT (3.2 MB < 4 MiB), so gathers are ~200-cyc
// L2 hits instead of LLC round trips. Streaming edge metadata and the out
// store use NONTEMPORAL accesses so they don't evict the resident slice.
// (Affinity is a perf heuristic; correctness is mapping-independent.)
// Within a wave: EDGE-QUAD (R6/R8-proven runtime loop, no conditional
// pipelining). Lane owns 4 cols (dword); four 16-lane groups each cover a
// full 64-B half-row -> one VMEM retires 4 edges. 8 shfl per 16-edge batch.
// Pad edges carry ws=0. Cross-quarter combine: shfl_xor 16/32.
__global__ __launch_bounds__(256) void scatter_kernel(const unsigned char* __restrict__ Tlo,
                                                      const unsigned char* __restrict__ Thi,
                                                      const float* __restrict__ S,
                                                      const int* __restrict__ esrc,
                                                      const float* __restrict__ ew,
                                                      const int* __restrict__ rp,
                                                      const float* __restrict__ b,
                                                      float* __restrict__ out,
                                                      int M, int ngroups) {
    const int blk = blockIdx.x;
    const int halfsel = (blk & 7) >> 2;            // 0: cols 0-63, 1: cols 64-127
    const int i = ((blk >> 3) << 2) + (blk & 3);   // node-group within half
    if (i >= ngroups) return;
    const int node = i * 4 + (threadIdx.x >> 6);
    if (node >= M) return;

    const unsigned char* __restrict__ T = halfsel ? Thi : Tlo;

    const int lane = threadIdx.x & 63;
    const int quarter = lane >> 4;                 // which edge of each quad
    const unsigned int colb = (lane & 15u) * 4u;   // byte offset in 64-B row

    const int s = __builtin_amdgcn_readfirstlane(rp[node]);
    const int e = __builtin_amdgcn_readfirstlane(rp[node + 1]);

    float a0 = 0.f, a1 = 0.f, a2 = 0.f, a3 = 0.f;
    float B = 0.f;              // sum of ws over this lane's edges

    for (int c = s; c < e; c += 64) {
        const int idx = c + lane;
        int srcl = 0;
        float wl = 0.f;
        if (idx < e) {                              // coalesced; pad w=0
            srcl = __builtin_nontemporal_load(esrc + idx);   // streaming: don't
            wl   = __builtin_nontemporal_load(ew + idx);     // pollute L2
        }
        const float wsl = wl * S[srcl];             // vector-pipe gather (cached)
        int nn = e - c;
        if (nn > 64) nn = 64;

        for (int j = 0; j < nn; j += 16) {   // 16 edges per batch (4/quad-group)
            int sq[4];
            float ws[4];
            unsigned int vv[4];
#pragma unroll
            for (int p = 0; p < 4; ++p) {
                const int sl = j + p * 4 + quarter;        // my group's edge
                sq[p] = __shfl(srcl, sl);                  // ds_bpermute
                ws[p] = __shfl(wsl, sl);
            }
#pragma unroll
            for (int p = 0; p < 4; ++p)
                vv[p] = *(const unsigned int*)(T + ((unsigned int)sq[p] * 64u + colb));
#pragma unroll
            for (int p = 0; p < 4; ++p) {
                const unsigned int v = vv[p];
                const float w = ws[p];
                B  += w;
                a0 = fmaf((float)(v & 0xffu), w, a0);           // v_cvt_f32_ubyte0
                a1 = fmaf((float)((v >> 8) & 0xffu), w, a1);    // v_cvt_f32_ubyte1
                a2 = fmaf((float)((v >> 16) & 0xffu), w, a2);   // v_cvt_f32_ubyte2
                a3 = fmaf((float)(v >> 24), w, a3);             // v_cvt_f32_ubyte3
            }
        }
    }

    // Combine the 4 quarter-groups (lanes l, l^16, l^32, l^48 share cols).
    a0 += __shfl_xor(a0, 16); a0 += __shfl_xor(a0, 32);
    a1 += __shfl_xor(a1, 16); a1 += __shfl_xor(a1, 32);
    a2 += __shfl_xor(a2, 16); a2 += __shfl_xor(a2, 32);
    a3 += __shfl_xor(a3, 16); a3 += __shfl_xor(a3, 32);
    B  += __shfl_xor(B, 16);  B  += __shfl_xor(B, 32);

    if (quarter == 0) {
        const int outcol = halfsel * 64 + (lane & 15) * 4;
        const float4v bb = *(const float4v*)&b[outcol];
        float4v o;
        o[0] = fmaf(-128.0f, B, a0) + bb[0];
        o[1] = fmaf(-128.0f, B, a1) + bb[1];
        o[2] = fmaf(-128.0f, B, a2) + bb[2];
        o[3] = fmaf(-128.0f, B, a3) + bb[3];
        __builtin_nontemporal_store(o, (float4v*)&out[node * 128 + outcol]);
    }
}

extern "C" void kernel_launch(void* const* d_in, const int* in_sizes, int n_in,
                              void* d_out, int out_size, void* d_ws, size_t ws_size,
                              hipStream_t stream) {
    const float* H    = (const float*)d_in[0];
    const int*   esrc = (const int*)d_in[1];
    const int*   edst = (const int*)d_in[2];
    const float* ew   = (const float*)d_in[3];
    const float* W    = (const float*)d_in[4];
    const float* b    = (const float*)d_in[5];
    float* out = (float*)d_out;

    const int M = in_sizes[0] / IN_DIM;   // 50000 nodes
    const int E = in_sizes[1];            // 1,600,000 edges

    // Workspace layout (~6.8 MB)
    unsigned char* Tlo = (unsigned char*)d_ws;                      // M*64 B (cols 0-63)
    size_t off = (size_t)M * 64;
    unsigned char* Thi = (unsigned char*)d_ws + off;                // M*64 B (cols 64-127)
    off += (size_t)M * 64;
    float* S  = (float*)((char*)d_ws + off);                        // M floats
    off += (size_t)M * 4;
    ushort* Wt = (ushort*)((char*)d_ws + off);                      // 128*136*2 B
    off += 128 * 136 * 2;
    int* rp = (int*)((char*)d_ws + off);                            // (M+1) ints

    // Wt transpose (16 blocks)
    prep_kernel<<<16, 256, 0, stream>>>(W, Wt);

    // gemm (split biased-uint8 output + per-row scale) + rp tail blocks
    const int nb_gemm = (M + 63) / 64;         // 782
    const int nb_rp   = (M + 1 + 255) / 256;   // 196
    gemm_kernel<<<nb_gemm + nb_rp, 256, 0, stream>>>(H, Wt, Tlo, Thi, S, M, edst, rp, E, nb_gemm);

    // scatter: 2 column-halves x node-groups of 4; mapping needs ngroups4 % 4 == 0
    const int ngroups  = (M + 3) / 4;                // 12500
    const int ngroups4 = ((ngroups + 3) / 4) * 4;    // 12500 (already /4)
    const int nblk     = 2 * ngroups4;               // 25000, divisible by 8
    scatter_kernel<<<nblk, 256, 0, stream>>>(Tlo, Thi, S, esrc, ew, rp, b, out, M, ngroups);
}

// Round 13
// 143.738 us; speedup vs baseline: 1.0763x; 1.0763x over previous
//
#include <hip/hip_runtime.h>

#define IN_DIM 128
#define OUT_DIM 128

typedef __attribute__((ext_vector_type(8))) short short8v;   // 8 bf16 = 4 VGPRs
typedef __attribute__((ext_vector_type(4))) float float4v;
typedef __attribute__((ext_vector_type(4))) unsigned int uint4v;

__device__ __forceinline__ ushort f2bf(float f) {
    unsigned int u = __builtin_bit_cast(unsigned int, f);
    unsigned int r = (u + 0x7fffu + ((u >> 16) & 1u)) >> 16;   // RNE
    return (ushort)r;
}

__device__ __forceinline__ unsigned int pk2bf(float x, float y) {
#if __has_builtin(__builtin_amdgcn_cvt_pk_bf16_f32)
    typedef __attribute__((ext_vector_type(2))) __bf16 bf2;
    bf2 r = __builtin_amdgcn_cvt_pk_bf16_f32(x, y);
    return __builtin_bit_cast(unsigned int, r);
#else
    return (unsigned int)f2bf(x) | ((unsigned int)f2bf(y) << 16);
#endif
}

// ---------------- Kernel 0: prep (Wt only, 16 blocks) ----------------
// Wt[n][k] = bf16(W[k][n]), row stride 136. Coalesced fp32 reads, b32 stores.
__global__ __launch_bounds__(256) void prep_kernel(const float* __restrict__ W,
                                                   ushort* __restrict__ Wt) {
    int k0 = blockIdx.x * 8;
    int n = threadIdx.x & 127;
    int half = threadIdx.x >> 7;
#pragma unroll
    for (int kp = 0; kp < 2; ++kp) {
        int k = k0 + (half * 2 + kp) * 2;
        float v0 = W[k * 128 + n];          // coalesced across lanes
        float v1 = W[(k + 1) * 128 + n];
        *(unsigned int*)&Wt[n * 136 + k] = pk2bf(v0, v1);
    }
}

// ---------------- Kernel 1: T(biased-uint8, per-row scale) = H @ W, + rp tail ----------------
// Blocks [0, nb_gemm): 64-row x 128-col tile, K=128 unrolled (proven core).
// Epilogue: per-row absmax (shfl_xor 16/32 over quarter-lanes), quantize row
// to BIASED uint8 (q+128), scale S[row] = rowmax/127. Output is SPLIT into
// two arrays (cols 0-63 -> Tlo, 64-127 -> Thi), each row 64 B, so each
// half is a physically separate 3.2 MB region that fits a 4-MiB XCD L2
// (R8's in-place column split failed: 64-B halves shared 128-B lines;
// R12 proved the split halves FETCH 64.6->29.6 MB).
// Blocks [nb_gemm, ...): row_ptr[n] = lower_bound(edst, n) (overlaps gemm).
__global__ __launch_bounds__(256) void gemm_kernel(const float* __restrict__ H,
                                                   const ushort* __restrict__ Wt_g,
                                                   unsigned char* __restrict__ Tlo,
                                                   unsigned char* __restrict__ Thi,
                                                   float* __restrict__ S, int M,
                                                   const int* __restrict__ edst,
                                                   int* __restrict__ rp,
                                                   int E, int nb_gemm) {
    __shared__ ushort Ws[128 * 136];   // 34816 B

    const int t = threadIdx.x;

    if (blockIdx.x >= nb_gemm) {       // rp tail blocks (block-uniform branch)
        int n = (blockIdx.x - nb_gemm) * 256 + t;
        if (n <= M) {
            int lo = 0, hi = E;
            while (lo < hi) {
                int mid = (lo + hi) >> 1;
                if (edst[mid] < n) lo = mid + 1; else hi = mid;
            }
            rp[n] = lo;
        }
        return;
    }

    const int row0 = blockIdx.x * 64;

#pragma unroll
    for (int f = t; f < 2176; f += 256)
        ((short8v*)Ws)[f] = ((const short8v*)Wt_g)[f];

    const int w = t >> 6;
    const int l = t & 63;
    const int m16 = l & 15;
    const int kq = (l >> 4) * 8;
    const int gr = row0 + w * 16 + m16;

    float4 h[8];
    if (gr < M) {
#pragma unroll
        for (int ks = 0; ks < 4; ++ks) {
            h[ks * 2]     = *(const float4*)&H[gr * 128 + ks * 32 + kq];
            h[ks * 2 + 1] = *(const float4*)&H[gr * 128 + ks * 32 + kq + 4];
        }
    } else {
#pragma unroll
        for (int i = 0; i < 8; ++i) h[i] = make_float4(0.f, 0.f, 0.f, 0.f);
    }

    short8v bfrag[4];
#pragma unroll
    for (int ks = 0; ks < 4; ++ks) {
        uint4v u;
        u[0] = pk2bf(h[ks * 2].x, h[ks * 2].y);
        u[1] = pk2bf(h[ks * 2].z, h[ks * 2].w);
        u[2] = pk2bf(h[ks * 2 + 1].x, h[ks * 2 + 1].y);
        u[3] = pk2bf(h[ks * 2 + 1].z, h[ks * 2 + 1].w);
        bfrag[ks] = __builtin_bit_cast(short8v, u);
    }

    __syncthreads();   // Ws ready

    float4v acc[8];
#pragma unroll
    for (int nt = 0; nt < 8; ++nt) acc[nt] = (float4v){0.f, 0.f, 0.f, 0.f};

#pragma unroll
    for (int ks = 0; ks < 4; ++ks) {
#pragma unroll
        for (int nt = 0; nt < 8; ++nt) {
            short8v afrag = *(const short8v*)&Ws[(nt * 16 + m16) * 136 + ks * 32 + kq];
            acc[nt] = __builtin_amdgcn_mfma_f32_16x16x32_bf16(afrag, bfrag[ks], acc[nt], 0, 0, 0);
        }
    }

    // Per-row absmax across this lane's 32 cols, then across the 4 quarter-
    // lanes sharing row gr (l, l^16, l^32, l^48).
    float mx = 0.f;
#pragma unroll
    for (int nt = 0; nt < 8; ++nt) {
#pragma unroll
        for (int k = 0; k < 4; ++k) mx = fmaxf(mx, fabsf(acc[nt][k]));
    }
    mx = fmaxf(mx, __shfl_xor(mx, 16));
    mx = fmaxf(mx, __shfl_xor(mx, 32));

    const float inv = 127.0f / fmaxf(mx, 1e-20f);

    if (gr < M) {
        const int qd = l >> 4;
        if (qd == 0) S[gr] = mx * (1.0f / 127.0f);
#pragma unroll
        for (int nt = 0; nt < 8; ++nt) {
            unsigned int p = 0;
#pragma unroll
            for (int k = 0; k < 4; ++k) {
                int qi = (int)__builtin_rintf(acc[nt][k] * inv);
                qi = qi > 127 ? 127 : (qi < -127 ? -127 : qi);
                p |= ((unsigned int)(qi + 128) & 0xffu) << (k * 8);   // biased
            }
            const int col = nt * 16 + qd * 4;
            if (nt < 4)
                *(unsigned int*)&Tlo[gr * 64 + col] = p;
            else
                *(unsigned int*)&Thi[gr * 64 + (col - 64)] = p;
        }
    }
}

// ---------------- Kernel 2: out[n][:] = b + sum_{e} w_e*S[src]*(T[src][:]-128) ----------------
// SPLIT-T + XCD AFFINITY: each block handles one 64-col half of 4 nodes,
// gathering from its half's PHYSICALLY SEPARATE 3.2 MB array (64-B rows).
// blockIdx&7 round-robins over XCDs -> XCDs 0-3 touch only Tlo, 4-7 only
// Thi; each slice is L2-RESIDENT (3.2 MB < 4 MiB) -- R12 measured FETCH
// 64.6->29.6 MB, confirming residency. Edge metadata uses NORMAL cached
// loads (R12's nontemporal metadata put a ~900-cyc uncacheable HBM load at
// the head of every chunk chain and regressed 38->59 us; the two halves
// share metadata through L2/LLC instead). Only the write-once out store
// stays nontemporal.
// Within a wave: EDGE-QUAD (R6-proven runtime loop, no conditional
// pipelining). Lane owns 4 cols (dword); four 16-lane groups each cover a
// full 64-B half-row -> one VMEM retires 4 edges. 8 shfl per 16-edge batch.
// Pad edges carry ws=0. Cross-quarter combine: shfl_xor 16/32.
__global__ __launch_bounds__(256) void scatter_kernel(const unsigned char* __restrict__ Tlo,
                                                      const unsigned char* __restrict__ Thi,
                                                      const float* __restrict__ S,
                                                      const int* __restrict__ esrc,
                                                      const float* __restrict__ ew,
                                                      const int* __restrict__ rp,
                                                      const float* __restrict__ b,
                                                      float* __restrict__ out,
                                                      int M, int ngroups) {
    const int blk = blockIdx.x;
    const int halfsel = (blk & 7) >> 2;            // 0: cols 0-63, 1: cols 64-127
    const int i = ((blk >> 3) << 2) + (blk & 3);   // node-group within half
    if (i >= ngroups) return;
    const int node = i * 4 + (threadIdx.x >> 6);
    if (node >= M) return;

    const unsigned char* __restrict__ T = halfsel ? Thi : Tlo;

    const int lane = threadIdx.x & 63;
    const int quarter = lane >> 4;                 // which edge of each quad
    const unsigned int colb = (lane & 15u) * 4u;   // byte offset in 64-B row

    const int s = __builtin_amdgcn_readfirstlane(rp[node]);
    const int e = __builtin_amdgcn_readfirstlane(rp[node + 1]);

    float a0 = 0.f, a1 = 0.f, a2 = 0.f, a3 = 0.f;
    float B = 0.f;              // sum of ws over this lane's edges

    for (int c = s; c < e; c += 64) {
        const int idx = c + lane;
        int srcl = 0;
        float wl = 0.f;
        if (idx < e) { srcl = esrc[idx]; wl = ew[idx]; }   // coalesced, cached
        const float wsl = wl * S[srcl];             // vector-pipe gather (cached)
        int nn = e - c;
        if (nn > 64) nn = 64;

        for (int j = 0; j < nn; j += 16) {   // 16 edges per batch (4/quad-group)
            int sq[4];
            float ws[4];
            unsigned int vv[4];
#pragma unroll
            for (int p = 0; p < 4; ++p) {
                const int sl = j + p * 4 + quarter;        // my group's edge
                sq[p] = __shfl(srcl, sl);                  // ds_bpermute
                ws[p] = __shfl(wsl, sl);
            }
#pragma unroll
            for (int p = 0; p < 4; ++p)
                vv[p] = *(const unsigned int*)(T + ((unsigned int)sq[p] * 64u + colb));
#pragma unroll
            for (int p = 0; p < 4; ++p) {
                const unsigned int v = vv[p];
                const float w = ws[p];
                B  += w;
                a0 = fmaf((float)(v & 0xffu), w, a0);           // v_cvt_f32_ubyte0
                a1 = fmaf((float)((v >> 8) & 0xffu), w, a1);    // v_cvt_f32_ubyte1
                a2 = fmaf((float)((v >> 16) & 0xffu), w, a2);   // v_cvt_f32_ubyte2
                a3 = fmaf((float)(v >> 24), w, a3);             // v_cvt_f32_ubyte3
            }
        }
    }

    // Combine the 4 quarter-groups (lanes l, l^16, l^32, l^48 share cols).
    a0 += __shfl_xor(a0, 16); a0 += __shfl_xor(a0, 32);
    a1 += __shfl_xor(a1, 16); a1 += __shfl_xor(a1, 32);
    a2 += __shfl_xor(a2, 16); a2 += __shfl_xor(a2, 32);
    a3 += __shfl_xor(a3, 16); a3 += __shfl_xor(a3, 32);
    B  += __shfl_xor(B, 16);  B  += __shfl_xor(B, 32);

    if (quarter == 0) {
        const int outcol = halfsel * 64 + (lane & 15) * 4;
        const float4v bb = *(const float4v*)&b[outcol];
        float4v o;
        o[0] = fmaf(-128.0f, B, a0) + bb[0];
        o[1] = fmaf(-128.0f, B, a1) + bb[1];
        o[2] = fmaf(-128.0f, B, a2) + bb[2];
        o[3] = fmaf(-128.0f, B, a3) + bb[3];
        __builtin_nontemporal_store(o, (float4v*)&out[node * 128 + outcol]);
    }
}

extern "C" void kernel_launch(void* const* d_in, const int* in_sizes, int n_in,
                              void* d_out, int out_size, void* d_ws, size_t ws_size,
                              hipStream_t stream) {
    const float* H    = (const float*)d_in[0];
    const int*   esrc = (const int*)d_in[1];
    const int*   edst = (const int*)d_in[2];
    const float* ew   = (const float*)d_in[3];
    const float* W    = (const float*)d_in[4];
    const float* b    = (const float*)d_in[5];
    float* out = (float*)d_out;

    const int M = in_sizes[0] / IN_DIM;   // 50000 nodes
    const int E = in_sizes[1];            // 1,600,000 edges

    // Workspace layout (~6.8 MB)
    unsigned char* Tlo = (unsigned char*)d_ws;                      // M*64 B (cols 0-63)
    size_t off = (size_t)M * 64;
    unsigned char* Thi = (unsigned char*)d_ws + off;                // M*64 B (cols 64-127)
    off += (size_t)M * 64;
    float* S  = (float*)((char*)d_ws + off);                        // M floats
    off += (size_t)M * 4;
    ushort* Wt = (ushort*)((char*)d_ws + off);                      // 128*136*2 B
    off += 128 * 136 * 2;
    int* rp = (int*)((char*)d_ws + off);                            // (M+1) ints

    // Wt transpose (16 blocks)
    prep_kernel<<<16, 256, 0, stream>>>(W, Wt);

    // gemm (split biased-uint8 output + per-row scale) + rp tail blocks
    const int nb_gemm = (M + 63) / 64;         // 782
    const int nb_rp   = (M + 1 + 255) / 256;   // 196
    gemm_kernel<<<nb_gemm + nb_rp, 256, 0, stream>>>(H, Wt, Tlo, Thi, S, M, edst, rp, E, nb_gemm);

    // scatter: 2 column-halves x node-groups of 4; mapping needs ngroups4 % 4 == 0
    const int ngroups  = (M + 3) / 4;                // 12500
    const int ngroups4 = ((ngroups + 3) / 4) * 4;    // 12500 (already /4)
    const int nblk     = 2 * ngroups4;               // 25000, divisible by 8
    scatter_kernel<<<nblk, 256, 0, stream>>>(Tlo, Thi, S, esrc, ew, rp, b, out, M, ngroups);
}

// Round 14
// 133.516 us; speedup vs baseline: 1.1587x; 1.0766x over previous
//
#include <hip/hip_runtime.h>

#define IN_DIM 128
#define OUT_DIM 128

typedef __attribute__((ext_vector_type(8))) short short8v;   // 8 bf16 = 4 VGPRs
typedef __attribute__((ext_vector_type(4))) float float4v;
typedef __attribute__((ext_vector_type(4))) unsigned int uint4v;

__device__ __forceinline__ ushort f2bf(float f) {
    unsigned int u = __builtin_bit_cast(unsigned int, f);
    unsigned int r = (u + 0x7fffu + ((u >> 16) & 1u)) >> 16;   // RNE
    return (ushort)r;
}

__device__ __forceinline__ unsigned int pk2bf(float x, float y) {
#if __has_builtin(__builtin_amdgcn_cvt_pk_bf16_f32)
    typedef __attribute__((ext_vector_type(2))) __bf16 bf2;
    bf2 r = __builtin_amdgcn_cvt_pk_bf16_f32(x, y);
    return __builtin_bit_cast(unsigned int, r);
#else
    return (unsigned int)f2bf(x) | ((unsigned int)f2bf(y) << 16);
#endif
}

// ---------------- Kernel 0: prep (Wt only, 16 blocks) ----------------
// Wt[n][k] = bf16(W[k][n]), row stride 136. Coalesced fp32 reads, b32 stores.
__global__ __launch_bounds__(256) void prep_kernel(const float* __restrict__ W,
                                                   ushort* __restrict__ Wt) {
    int k0 = blockIdx.x * 8;
    int n = threadIdx.x & 127;
    int half = threadIdx.x >> 7;
#pragma unroll
    for (int kp = 0; kp < 2; ++kp) {
        int k = k0 + (half * 2 + kp) * 2;
        float v0 = W[k * 128 + n];          // coalesced across lanes
        float v1 = W[(k + 1) * 128 + n];
        *(unsigned int*)&Wt[n * 136 + k] = pk2bf(v0, v1);
    }
}

// ---------------- Kernel 1: T(biased-uint8, per-row scale) = H @ W, + rp tail ----------------
// Blocks [0, nb_gemm): 64-row x 128-col tile, K=128 unrolled (proven core).
// Epilogue: per-row absmax (shfl_xor 16/32 over quarter-lanes), quantize row
// to BIASED uint8 (q+128) with scale S[row] = rowmax/127 -> fetch-cheap
// scatter gather AND single-instruction v_cvt_f32_ubyte decode.
// Blocks [nb_gemm, ...): row_ptr[n] = lower_bound(edst, n) (overlaps gemm).
__global__ __launch_bounds__(256) void gemm_kernel(const float* __restrict__ H,
                                                   const ushort* __restrict__ Wt_g,
                                                   unsigned char* __restrict__ T8,
                                                   float* __restrict__ S, int M,
                                                   const int* __restrict__ edst,
                                                   int* __restrict__ rp,
                                                   int E, int nb_gemm) {
    __shared__ ushort Ws[128 * 136];   // 34816 B

    const int t = threadIdx.x;

    if (blockIdx.x >= nb_gemm) {       // rp tail blocks (block-uniform branch)
        int n = (blockIdx.x - nb_gemm) * 256 + t;
        if (n <= M) {
            int lo = 0, hi = E;
            while (lo < hi) {
                int mid = (lo + hi) >> 1;
                if (edst[mid] < n) lo = mid + 1; else hi = mid;
            }
            rp[n] = lo;
        }
        return;
    }

    const int row0 = blockIdx.x * 64;

#pragma unroll
    for (int f = t; f < 2176; f += 256)
        ((short8v*)Ws)[f] = ((const short8v*)Wt_g)[f];

    const int w = t >> 6;
    const int l = t & 63;
    const int m16 = l & 15;
    const int kq = (l >> 4) * 8;
    const int gr = row0 + w * 16 + m16;

    float4 h[8];
    if (gr < M) {
#pragma unroll
        for (int ks = 0; ks < 4; ++ks) {
            h[ks * 2]     = *(const float4*)&H[gr * 128 + ks * 32 + kq];
            h[ks * 2 + 1] = *(const float4*)&H[gr * 128 + ks * 32 + kq + 4];
        }
    } else {
#pragma unroll
        for (int i = 0; i < 8; ++i) h[i] = make_float4(0.f, 0.f, 0.f, 0.f);
    }

    short8v bfrag[4];
#pragma unroll
    for (int ks = 0; ks < 4; ++ks) {
        uint4v u;
        u[0] = pk2bf(h[ks * 2].x, h[ks * 2].y);
        u[1] = pk2bf(h[ks * 2].z, h[ks * 2].w);
        u[2] = pk2bf(h[ks * 2 + 1].x, h[ks * 2 + 1].y);
        u[3] = pk2bf(h[ks * 2 + 1].z, h[ks * 2 + 1].w);
        bfrag[ks] = __builtin_bit_cast(short8v, u);
    }

    __syncthreads();   // Ws ready

    float4v acc[8];
#pragma unroll
    for (int nt = 0; nt < 8; ++nt) acc[nt] = (float4v){0.f, 0.f, 0.f, 0.f};

#pragma unroll
    for (int ks = 0; ks < 4; ++ks) {
#pragma unroll
        for (int nt = 0; nt < 8; ++nt) {
            short8v afrag = *(const short8v*)&Ws[(nt * 16 + m16) * 136 + ks * 32 + kq];
            acc[nt] = __builtin_amdgcn_mfma_f32_16x16x32_bf16(afrag, bfrag[ks], acc[nt], 0, 0, 0);
        }
    }

    // Per-row absmax across this lane's 32 cols, then across the 4 quarter-
    // lanes sharing row gr (l, l^16, l^32, l^48).
    float mx = 0.f;
#pragma unroll
    for (int nt = 0; nt < 8; ++nt) {
#pragma unroll
        for (int k = 0; k < 4; ++k) mx = fmaxf(mx, fabsf(acc[nt][k]));
    }
    mx = fmaxf(mx, __shfl_xor(mx, 16));
    mx = fmaxf(mx, __shfl_xor(mx, 32));

    const float inv = 127.0f / fmaxf(mx, 1e-20f);

    if (gr < M) {
        const int qd = l >> 4;
        if (qd == 0) S[gr] = mx * (1.0f / 127.0f);
#pragma unroll
        for (int nt = 0; nt < 8; ++nt) {
            unsigned int p = 0;
#pragma unroll
            for (int k = 0; k < 4; ++k) {
                int qi = (int)__builtin_rintf(acc[nt][k] * inv);
                qi = qi > 127 ? 127 : (qi < -127 ? -127 : qi);
                p |= ((unsigned int)(qi + 128) & 0xffu) << (k * 8);   // biased
            }
            *(unsigned int*)&T8[gr * 128 + nt * 16 + qd * 4] = p;
        }
    }
}

// ---------------- Kernel 2: out[n][:] = b + sum_{e} w_e*S[src]*(T8[src][:]-128) ----------------
// One wave per node, EDGE-PAIR structure (R6, best verified): lane owns 4
// cols (one dword of a row). Lanes 0-31 read the EVEN edge's full 128-B row
// (= 1 cache line), lanes 32-63 the ODD edge's -> one VMEM retires 2 edges.
// Metadata select per pair: 2 __shfl (ds_bpermute on the LDS pipe) + 1 add.
// Chunk loads use the weight-0 pad (no serial tail); the S[src] gather runs
// on the vector pipe (L2-resident). Runtime inner loop, self-contained
// batches (conditional issue/decode separation forces vmcnt(0) -- R7).
// Per edge: ~5.5 VALU + 1 DS + 0.5 VMEM. Cross-half combine: shfl_xor(32);
// lanes 0-31 store float4. Bias correction -128*B applied once at the end.
//
// Tried and rejected (all measured): R7 static 4-batch pipelining (-4.5us,
// guarded VMEM -> conservative vmcnt(0)); R8 in-place col-split (-15us,
// halves share 128-B lines, footprint unchanged); R9 two-node ILP (-2.4us,
// resident waves already cover latency); R12/R13 split-T L2-residency
// (FETCH 64.6->36.6 MB proven, but doubled per-node chain count -> -11us).
__global__ __launch_bounds__(256) void scatter_kernel(const unsigned char* __restrict__ T8,
                                                      const float* __restrict__ S,
                                                      const int* __restrict__ esrc,
                                                      const float* __restrict__ ew,
                                                      const int* __restrict__ rp,
                                                      const float* __restrict__ b,
                                                      float* __restrict__ out) {
    const int node = blockIdx.x * 4 + (threadIdx.x >> 6);
    const int lane = threadIdx.x & 63;
    const int half = lane >> 5;                       // 0: even edges, 1: odd edges
    const unsigned int colb = (lane & 31u) * 4u;      // byte (=col) offset in row

    const int s = __builtin_amdgcn_readfirstlane(rp[node]);
    const int e = __builtin_amdgcn_readfirstlane(rp[node + 1]);

    float ax0 = 0.f, ax1 = 0.f, ax2 = 0.f, ax3 = 0.f;
    float B = 0.f;              // sum of ws over THIS lane's (half's) edges

    for (int c = s; c < e; c += 64) {
        const int idx = c + lane;
        int srcl = 0;
        float wl = 0.f;
        if (idx < e) { srcl = esrc[idx]; wl = ew[idx]; }   // coalesced
        const float wsl = wl * S[srcl];                    // vector-pipe gather
        int nn = e - c;
        if (nn > 64) nn = 64;

        for (int j = 0; j < nn; j += 8) {   // 4 pairs per batch; pad ws=0
            int sqp[4];
            float wsp[4];
            unsigned int vv[4];
#pragma unroll
            for (int p = 0; p < 4; ++p) {
                const int srcLane = j + p * 2 + half;      // my half's edge
                sqp[p] = __shfl(srcl, srcLane);            // ds_bpermute
                wsp[p] = __shfl(wsl, srcLane);             // ds_bpermute
            }
#pragma unroll
            for (int p = 0; p < 4; ++p)
                vv[p] = *(const unsigned int*)(T8 + ((unsigned int)sqp[p] * 128u + colb));
#pragma unroll
            for (int p = 0; p < 4; ++p) {
                const unsigned int v = vv[p];
                const float ws = wsp[p];
                B += ws;
                ax0 = fmaf((float)(v & 0xffu), ws, ax0);           // v_cvt_f32_ubyte0
                ax1 = fmaf((float)((v >> 8) & 0xffu), ws, ax1);    // v_cvt_f32_ubyte1
                ax2 = fmaf((float)((v >> 16) & 0xffu), ws, ax2);   // v_cvt_f32_ubyte2
                ax3 = fmaf((float)(v >> 24), ws, ax3);             // v_cvt_f32_ubyte3
            }
        }
    }

    // Combine even-edge half (lanes 0-31) with odd-edge half (lanes 32-63).
    ax0 += __shfl_xor(ax0, 32);
    ax1 += __shfl_xor(ax1, 32);
    ax2 += __shfl_xor(ax2, 32);
    ax3 += __shfl_xor(ax3, 32);
    B   += __shfl_xor(B, 32);

    if (half == 0) {
        const float4 bb = *(const float4*)&b[colb];
        float4 o;
        o.x = fmaf(-128.0f, B, ax0) + bb.x;
        o.y = fmaf(-128.0f, B, ax1) + bb.y;
        o.z = fmaf(-128.0f, B, ax2) + bb.z;
        o.w = fmaf(-128.0f, B, ax3) + bb.w;
        *(float4*)&out[node * 128 + colb] = o;
    }
}

extern "C" void kernel_launch(void* const* d_in, const int* in_sizes, int n_in,
                              void* d_out, int out_size, void* d_ws, size_t ws_size,
                              hipStream_t stream) {
    const float* H    = (const float*)d_in[0];
    const int*   esrc = (const int*)d_in[1];
    const int*   edst = (const int*)d_in[2];
    const float* ew   = (const float*)d_in[3];
    const float* W    = (const float*)d_in[4];
    const float* b    = (const float*)d_in[5];
    float* out = (float*)d_out;

    const int M = in_sizes[0] / IN_DIM;   // 50000 nodes
    const int E = in_sizes[1];            // 1,600,000 edges

    // Workspace layout (~6.8 MB)
    unsigned char* T8 = (unsigned char*)d_ws;                       // M*128 B (biased uint8)
    size_t off = (size_t)M * 128;
    float* S  = (float*)((char*)d_ws + off);                        // M floats
    off += (size_t)M * 4;
    ushort* Wt = (ushort*)((char*)d_ws + off);                      // 128*136*2 B
    off += 128 * 136 * 2;
    int* rp = (int*)((char*)d_ws + off);                            // (M+1) ints

    // Wt transpose (16 blocks)
    prep_kernel<<<16, 256, 0, stream>>>(W, Wt);

    // gemm (biased-uint8 output + per-row scale) + rp tail blocks
    const int nb_gemm = (M + 63) / 64;         // 782
    const int nb_rp   = (M + 1 + 255) / 256;   // 196
    gemm_kernel<<<nb_gemm + nb_rp, 256, 0, stream>>>(H, Wt, T8, S, M, edst, rp, E, nb_gemm);

    scatter_kernel<<<(M + 3) / 4, 256, 0, stream>>>(T8, S, esrc, ew, rp, b, out);
}